// Round 1
// baseline (1169.860 us; speedup 1.0000x reference)
//
#include <hip/hip_runtime.h>
#include <math.h>

// MultiHeadAttention: x[1,4096,1024] fp32, Wq/Wk/Wv[1024,1024], Wo[1024,1024].
// Outputs (concat in d_out): y[4096*1024] fp32, attn[8*4096*4096] fp32.
//
// R3 structure (= R2 + pipelined pv_norm):
//   split x / transpose weights -> Q,K proj (split-bf16, fused z=2 launch),
//   V proj + transpose -> qk_exp (split QK, exp, bf16 store + rowsums) ->
//   reciprocal -> pv_norm (2-deep expS register prefetch, double-buffered
//   LDS, 1 barrier/panel, nontemporal attn stores) -> Wo proj.
// expS bf16 scratch (268 MB) lives in ws if it fits, else fp32 in-place in
// the attn output region (template fallback).

typedef unsigned short u16;
typedef __attribute__((ext_vector_type(8))) short bf16x8;
typedef __attribute__((ext_vector_type(4))) float f32x4;

#define SEQ 4096
#define FDIM 1024
#define NHEAD 8
#define DK 128

__device__ __forceinline__ u16 f2bf(float f) {
  unsigned u = __float_as_uint(f);
  u += 0x7fffu + ((u >> 16) & 1u);  // round-to-nearest-even
  return (u16)(u >> 16);
}
__device__ __forceinline__ float bf2f(u16 h) {
  return __uint_as_float(((unsigned)h) << 16);
}

__device__ __forceinline__ void g2l16(const void* g, void* l) {
  __builtin_amdgcn_global_load_lds(
      (const __attribute__((address_space(1))) void*)g,
      (__attribute__((address_space(3))) void*)l, 16, 0, 0);
}

// ---------------------------------------------------------------- prep kernels

__global__ void split_f32_bf16(const float4* __restrict__ in, u16* __restrict__ ohi,
                               u16* __restrict__ olo, int n4) {
  int i = blockIdx.x * 256 + threadIdx.x;
  if (i >= n4) return;
  float4 v = in[i];
  u16 h0 = f2bf(v.x), h1 = f2bf(v.y), h2 = f2bf(v.z), h3 = f2bf(v.w);
  u16 l0 = f2bf(v.x - bf2f(h0)), l1 = f2bf(v.y - bf2f(h1));
  u16 l2 = f2bf(v.z - bf2f(h2)), l3 = f2bf(v.w - bf2f(h3));
  *(ushort4*)(ohi + 4 * (size_t)i) = make_ushort4(h0, h1, h2, h3);
  *(ushort4*)(olo + 4 * (size_t)i) = make_ushort4(l0, l1, l2, l3);
}

// out[n][k] = in[k][n], 1024x1024, optional split
__global__ void transpose_split_w(const float* __restrict__ in, u16* __restrict__ ohi,
                                  u16* __restrict__ olo, int dim, int do_split) {
  __shared__ float t[32][33];
  int tx = threadIdx.x, ty = threadIdx.y;
  int x = blockIdx.x * 32 + tx;
  int y0 = blockIdx.y * 32;
  for (int j = ty; j < 32; j += 8) t[j][tx] = in[(long)(y0 + j) * dim + x];
  __syncthreads();
  int x2 = y0 + tx;
  int y2 = blockIdx.x * 32;
  for (int j = ty; j < 32; j += 8) {
    float v = t[tx][j];
    u16 hi = f2bf(v);
    ohi[(long)(y2 + j) * dim + x2] = hi;
    if (do_split) olo[(long)(y2 + j) * dim + x2] = f2bf(v - bf2f(hi));
  }
}

__global__ void transpose_bf16(const u16* __restrict__ in, u16* __restrict__ out,
                               int rows, int cols) {
  __shared__ u16 t[32][33];
  int tx = threadIdx.x, ty = threadIdx.y;
  int x = blockIdx.x * 32 + tx;
  int y0 = blockIdx.y * 32;
  for (int j = ty; j < 32; j += 8) t[j][tx] = in[(long)(y0 + j) * cols + x];
  __syncthreads();
  int x2 = y0 + tx;
  int y2 = blockIdx.x * 32;
  for (int j = ty; j < 32; j += 8) out[(long)(y2 + j) * rows + x2] = t[tx][j];
}

__global__ void reciprocal_k(const float* __restrict__ in, float* __restrict__ out, int n) {
  int i = blockIdx.x * 256 + threadIdx.x;
  if (i < n) out[i] = 1.0f / in[i];
}

// ---------------------------------------------------------------- projection GEMM (C = A * B^T)
// EPI: 0 = fp32 store, 1 = bf16 store, 2 = split bf16 store
template <int BK, bool SPLIT, int EPI>
__global__ __launch_bounds__(256, 2) void gemm_bt(
    const u16* Ahi_, const u16* Alo_,
    const u16* Bhi_, const u16* Blo_,
    void* C0, void* C1,
    int Kdim, int lda, int ldb, int ldc,
    long aStrH, long bStrH, long cStrH) {
  constexpr int LDSN = 128 * BK;
  __shared__ u16 sAhi[LDSN];
  __shared__ u16 sBhi[LDSN];
  __shared__ u16 sAlo[SPLIT ? LDSN : 2];
  __shared__ u16 sBlo[SPLIT ? LDSN : 2];

  const int tid = threadIdx.x;
  const int lane = tid & 63;
  const int wave = tid >> 6;
  const int wr = wave >> 1, wc = wave & 1;
  const int quad = lane >> 4, l16 = lane & 15;
  const int h = blockIdx.z;
  const long bm = (long)blockIdx.y * 128;
  const long bn = (long)blockIdx.x * 128;

  const u16* Ahi = Ahi_ + (long)h * aStrH;
  const u16* Alo = SPLIT ? (Alo_ + (long)h * aStrH) : nullptr;
  const u16* Bhi = Bhi_ + (long)h * bStrH;
  const u16* Blo = SPLIT ? (Blo_ + (long)h * bStrH) : nullptr;

  f32x4 acc[4][4];
#pragma unroll
  for (int i = 0; i < 4; i++)
#pragma unroll
    for (int j = 0; j < 4; j++) acc[i][j] = (f32x4)0.0f;

  for (int k0 = 0; k0 < Kdim; k0 += BK) {
    constexpr int GR = (128 * BK) / (256 * 8);
#pragma unroll
    for (int r = 0; r < GR; ++r) {
      int e = (r * 256 + tid) * 8;
      int row = e / BK, col = e % BK;
      long ga = (bm + row) * (long)lda + k0 + col;
      long gb = (bn + row) * (long)ldb + k0 + col;
      g2l16(Ahi + ga, (char*)sAhi + (size_t)e * 2);
      g2l16(Bhi + gb, (char*)sBhi + (size_t)e * 2);
      if constexpr (SPLIT) {
        g2l16(Alo + ga, (char*)sAlo + (size_t)e * 2);
        g2l16(Blo + gb, (char*)sBlo + (size_t)e * 2);
      }
    }
    __syncthreads();

#pragma unroll
    for (int ks = 0; ks < BK; ks += 32) {
      bf16x8 aH[4], bH[4];
      bf16x8 aL[SPLIT ? 4 : 1], bL[SPLIT ? 4 : 1];
#pragma unroll
      for (int mi = 0; mi < 4; mi++) {
        int off = (wr * 64 + mi * 16 + l16) * BK + ks + quad * 8;
        aH[mi] = *(const bf16x8*)&sAhi[off];
        if constexpr (SPLIT) aL[mi] = *(const bf16x8*)&sAlo[off];
      }
#pragma unroll
      for (int ni = 0; ni < 4; ni++) {
        int off = (wc * 64 + ni * 16 + l16) * BK + ks + quad * 8;
        bH[ni] = *(const bf16x8*)&sBhi[off];
        if constexpr (SPLIT) bL[ni] = *(const bf16x8*)&sBlo[off];
      }
#pragma unroll
      for (int mi = 0; mi < 4; mi++)
#pragma unroll
        for (int ni = 0; ni < 4; ni++) {
          acc[mi][ni] = __builtin_amdgcn_mfma_f32_16x16x32_bf16(aH[mi], bH[ni], acc[mi][ni], 0, 0, 0);
          if constexpr (SPLIT) {
            acc[mi][ni] = __builtin_amdgcn_mfma_f32_16x16x32_bf16(aH[mi], bL[ni], acc[mi][ni], 0, 0, 0);
            acc[mi][ni] = __builtin_amdgcn_mfma_f32_16x16x32_bf16(aL[mi], bH[ni], acc[mi][ni], 0, 0, 0);
          }
        }
    }
    __syncthreads();
  }

  const long rowB = bm + wr * 64;
  const long colB = bn + wc * 64;
  if constexpr (EPI == 2) {
    u16* Chi = (u16*)C0 + (long)h * cStrH;
    u16* Clo = (u16*)C1 + (long)h * cStrH;
#pragma unroll
    for (int mi = 0; mi < 4; mi++)
#pragma unroll
      for (int ni = 0; ni < 4; ni++) {
        long col = colB + ni * 16 + l16;
#pragma unroll
        for (int r = 0; r < 4; r++) {
          long idx = (rowB + mi * 16 + quad * 4 + r) * (long)ldc + col;
          float v = acc[mi][ni][r];
          u16 hi = f2bf(v);
          Chi[idx] = hi;
          Clo[idx] = f2bf(v - bf2f(hi));
        }
      }
  } else if constexpr (EPI == 1) {
    u16* C = (u16*)C0 + (long)h * cStrH;
#pragma unroll
    for (int mi = 0; mi < 4; mi++)
#pragma unroll
      for (int ni = 0; ni < 4; ni++) {
        long col = colB + ni * 16 + l16;
#pragma unroll
        for (int r = 0; r < 4; r++)
          C[(rowB + mi * 16 + quad * 4 + r) * (long)ldc + col] = f2bf(acc[mi][ni][r]);
      }
  } else {
    float* C = (float*)C0 + (long)h * cStrH;
#pragma unroll
    for (int mi = 0; mi < 4; mi++)
#pragma unroll
      for (int ni = 0; ni < 4; ni++) {
        long col = colB + ni * 16 + l16;
#pragma unroll
        for (int r = 0; r < 4; r++)
          C[(rowB + mi * 16 + quad * 4 + r) * (long)ldc + col] = acc[mi][ni][r];
      }
  }
}

// ---------------------------------------------------------------- QK^T + exp
// S = exp(scale * Q K^T) per head; stores bf16 (or fp32 fallback) + rowsums.
// Q,K: [4096][1024] split bf16; head h = cols [h*128, h*128+128).
template <bool BF16S>
__global__ __launch_bounds__(256, 2) void qk_exp(
    const u16* __restrict__ Qhi, const u16* __restrict__ Qlo,
    const u16* __restrict__ Khi, const u16* __restrict__ Klo,
    void* __restrict__ outE, float* __restrict__ rowSum, float scale) {
  __shared__ u16 smem[32768];  // 64 KB: staging; first 32 KB reused as P-buf
  u16* sQh = smem;
  u16* sQl = smem + 8192;
  u16* sKh = smem + 16384;
  u16* sKl = smem + 24576;

  const int tid = threadIdx.x;
  const int lane = tid & 63, wave = tid >> 6;
  const int wr = wave >> 1, wc = wave & 1;
  const int quad = lane >> 4, l16 = lane & 15;
  const int h = blockIdx.z;
  const int bm = blockIdx.y * 128, bn = blockIdx.x * 128;
  const int colOff = h * DK;

  f32x4 acc[4][4];
#pragma unroll
  for (int i = 0; i < 4; i++)
#pragma unroll
    for (int j = 0; j < 4; j++) acc[i][j] = (f32x4)0.0f;

  for (int k0 = 0; k0 < DK; k0 += 64) {
#pragma unroll
    for (int r = 0; r < 4; ++r) {
      int e = (r * 256 + tid) * 8;
      int row = e >> 6, col = e & 63;
      long gq = (long)(bm + row) * FDIM + colOff + k0 + col;
      long gk = (long)(bn + row) * FDIM + colOff + k0 + col;
      g2l16(Qhi + gq, (char*)sQh + (size_t)e * 2);
      g2l16(Qlo + gq, (char*)sQl + (size_t)e * 2);
      g2l16(Khi + gk, (char*)sKh + (size_t)e * 2);
      g2l16(Klo + gk, (char*)sKl + (size_t)e * 2);
    }
    __syncthreads();
#pragma unroll
    for (int ks = 0; ks < 64; ks += 32) {
      bf16x8 aH[4], aL[4], bH[4], bL[4];
#pragma unroll
      for (int i = 0; i < 4; i++) {
        int offA = (wr * 64 + i * 16 + l16) * 64 + ks + quad * 8;
        int offB = (wc * 64 + i * 16 + l16) * 64 + ks + quad * 8;
        aH[i] = *(const bf16x8*)&sQh[offA];
        aL[i] = *(const bf16x8*)&sQl[offA];
        bH[i] = *(const bf16x8*)&sKh[offB];
        bL[i] = *(const bf16x8*)&sKl[offB];
      }
#pragma unroll
      for (int mi = 0; mi < 4; mi++)
#pragma unroll
        for (int ni = 0; ni < 4; ni++) {
          acc[mi][ni] = __builtin_amdgcn_mfma_f32_16x16x32_bf16(aH[mi], bH[ni], acc[mi][ni], 0, 0, 0);
          acc[mi][ni] = __builtin_amdgcn_mfma_f32_16x16x32_bf16(aH[mi], bL[ni], acc[mi][ni], 0, 0, 0);
          acc[mi][ni] = __builtin_amdgcn_mfma_f32_16x16x32_bf16(aL[mi], bH[ni], acc[mi][ni], 0, 0, 0);
        }
    }
    __syncthreads();
  }

  // exp in place + per-row sums (shfl over the 16 col-lanes, atomic per block)
#pragma unroll
  for (int mi = 0; mi < 4; mi++) {
    f32x4 rs = (f32x4)0.0f;
#pragma unroll
    for (int ni = 0; ni < 4; ni++)
#pragma unroll
      for (int r = 0; r < 4; r++) {
        float e = __expf(acc[mi][ni][r] * scale);
        acc[mi][ni][r] = e;
        rs[r] += e;
      }
#pragma unroll
    for (int m = 1; m < 16; m <<= 1) {
      rs[0] += __shfl_xor(rs[0], m);
      rs[1] += __shfl_xor(rs[1], m);
      rs[2] += __shfl_xor(rs[2], m);
      rs[3] += __shfl_xor(rs[3], m);
    }
    if (l16 == 0) {
      int rbase = h * SEQ + bm + wr * 64 + mi * 16 + quad * 4;
#pragma unroll
      for (int r = 0; r < 4; r++) atomicAdd(&rowSum[rbase + r], rs[r]);
    }
  }

  // transpose tile through LDS for vectorized stores
  u16* P = smem;  // 128x128 bf16 = 32 KB (staging no longer needed)
#pragma unroll
  for (int mi = 0; mi < 4; mi++)
#pragma unroll
    for (int ni = 0; ni < 4; ni++)
#pragma unroll
      for (int r = 0; r < 4; r++)
        P[(wr * 64 + mi * 16 + quad * 4 + r) * 128 + wc * 64 + ni * 16 + l16] =
            f2bf(acc[mi][ni][r]);
  __syncthreads();

  if constexpr (BF16S) {
    u16* out = (u16*)outE + ((long)h << 24);
#pragma unroll
    for (int j = 0; j < 8; ++j) {
      int e = (j * 256 + tid) * 8;
      int row = e >> 7, col = e & 127;
      long g = (long)(bm + row) * SEQ + bn + col;
      *(uint4*)(out + g) = *(const uint4*)(P + e);
    }
  } else {
    float* out = (float*)outE + ((long)h << 24);
#pragma unroll
    for (int j = 0; j < 16; ++j) {
      int e = (j * 256 + tid) * 4;
      int row = e >> 7, col = e & 127;
      long g = (long)(bm + row) * SEQ + bn + col;
      ushort4 u = *(const ushort4*)(P + e);
      *(float4*)(out + g) = make_float4(bf2f(u.x), bf2f(u.y), bf2f(u.z), bf2f(u.w));
    }
  }
}

// ---------------------------------------------------------------- PV + attn normalize
// Reads expS, multiplies by invRow, writes final fp32 attn (nontemporal), and
// computes y = P_norm @ V via MFMA (Vt = V^T [1024][4096]). 64-row blocks.
// R3: 2-deep register prefetch of expS panels (regsets A/B), double-buffered
// sP/sV LDS, one barrier per panel.
template <bool BF16S>
__global__ __launch_bounds__(256, 2) void pv_norm(
    const void* __restrict__ expS, const float* __restrict__ invRow,
    float* __restrict__ attnOut, const u16* __restrict__ Vt,
    u16* __restrict__ Yb) {
  __shared__ u16 sP[2][64 * 64];   // 2 x 8 KB
  __shared__ u16 sV[2][128 * 64];  // 2 x 16 KB
  const int tid = threadIdx.x;
  const int lane = tid & 63, wave = tid >> 6;
  const int wr = wave >> 1, wc = wave & 1;
  const int quad = lane >> 4, l16 = lane & 15;
  const int h = blockIdx.z;
  const int bm = blockIdx.y * 64;

  // per-thread fixed geometry for the two 8-element expS chunks
  const int e0 = tid * 8, e1 = (256 + tid) * 8;
  const int row0 = e0 >> 6, col0 = e0 & 63;
  const int row1 = e1 >> 6, col1 = e1 & 63;
  const long arow0 = (long)h * SEQ + bm + row0;
  const long arow1 = (long)h * SEQ + bm + row1;
  const float inv0 = invRow[arow0];
  const float inv1 = invRow[arow1];

  f32x4 acc[2][4];
#pragma unroll
  for (int i = 0; i < 2; i++)
#pragma unroll
    for (int j = 0; j < 4; j++) acc[i][j] = (f32x4)0.0f;

  // register sets for 2-deep expS prefetch (named, statically indexed)
  bf16x8 pbA0, pbA1, pbB0, pbB1;                      // BF16S path
  f32x4 pfA0, pfA1, pfA2, pfA3, pfB0, pfB1, pfB2, pfB3;  // fp32 fallback

#define LOADP(S, k0)                                                           \
  do {                                                                         \
    if constexpr (BF16S) {                                                     \
      const u16* _s = (const u16*)expS;                                        \
      pb##S##0 = __builtin_nontemporal_load(                                   \
          (const bf16x8*)(_s + arow0 * SEQ + (k0) + col0));                    \
      pb##S##1 = __builtin_nontemporal_load(                                   \
          (const bf16x8*)(_s + arow1 * SEQ + (k0) + col1));                    \
    } else {                                                                   \
      const float* _s = (const float*)expS;                                    \
      pf##S##0 = __builtin_nontemporal_load(                                   \
          (const f32x4*)(_s + arow0 * SEQ + (k0) + col0));                     \
      pf##S##1 = __builtin_nontemporal_load(                                   \
          (const f32x4*)(_s + arow0 * SEQ + (k0) + col0 + 4));                 \
      pf##S##2 = __builtin_nontemporal_load(                                   \
          (const f32x4*)(_s + arow1 * SEQ + (k0) + col1));                     \
      pf##S##3 = __builtin_nontemporal_load(                                   \
          (const f32x4*)(_s + arow1 * SEQ + (k0) + col1 + 4));                 \
    }                                                                          \
  } while (0)

#define PROC(S, k0, buf)                                                       \
  do {                                                                         \
    float p0[8], p1[8];                                                        \
    if constexpr (BF16S) {                                                     \
      p0[0] = bf2f((u16)pb##S##0[0]) * inv0;                                   \
      p0[1] = bf2f((u16)pb##S##0[1]) * inv0;                                   \
      p0[2] = bf2f((u16)pb##S##0[2]) * inv0;                                   \
      p0[3] = bf2f((u16)pb##S##0[3]) * inv0;                                   \
      p0[4] = bf2f((u16)pb##S##0[4]) * inv0;                                   \
      p0[5] = bf2f((u16)pb##S##0[5]) * inv0;                                   \
      p0[6] = bf2f((u16)pb##S##0[6]) * inv0;                                   \
      p0[7] = bf2f((u16)pb##S##0[7]) * inv0;                                   \
      p1[0] = bf2f((u16)pb##S##1[0]) * inv1;                                   \
      p1[1] = bf2f((u16)pb##S##1[1]) * inv1;                                   \
      p1[2] = bf2f((u16)pb##S##1[2]) * inv1;                                   \
      p1[3] = bf2f((u16)pb##S##1[3]) * inv1;                                   \
      p1[4] = bf2f((u16)pb##S##1[4]) * inv1;                                   \
      p1[5] = bf2f((u16)pb##S##1[5]) * inv1;                                   \
      p1[6] = bf2f((u16)pb##S##1[6]) * inv1;                                   \
      p1[7] = bf2f((u16)pb##S##1[7]) * inv1;                                   \
    } else {                                                                   \
      p0[0] = pf##S##0[0] * inv0; p0[1] = pf##S##0[1] * inv0;                  \
      p0[2] = pf##S##0[2] * inv0; p0[3] = pf##S##0[3] * inv0;                  \
      p0[4] = pf##S##1[0] * inv0; p0[5] = pf##S##1[1] * inv0;                  \
      p0[6] = pf##S##1[2] * inv0; p0[7] = pf##S##1[3] * inv0;                  \
      p1[0] = pf##S##2[0] * inv1; p1[1] = pf##S##2[1] * inv1;                  \
      p1[2] = pf##S##2[2] * inv1; p1[3] = pf##S##2[3] * inv1;                  \
      p1[4] = pf##S##3[0] * inv1; p1[5] = pf##S##3[1] * inv1;                  \
      p1[6] = pf##S##3[2] * inv1; p1[7] = pf##S##3[3] * inv1;                  \
    }                                                                          \
    long _g0 = arow0 * SEQ + (k0) + col0;                                      \
    long _g1 = arow1 * SEQ + (k0) + col1;                                      \
    f32x4 _w0 = {p0[0], p0[1], p0[2], p0[3]};                                  \
    f32x4 _w1 = {p0[4], p0[5], p0[6], p0[7]};                                  \
    f32x4 _w2 = {p1[0], p1[1], p1[2], p1[3]};                                  \
    f32x4 _w3 = {p1[4], p1[5], p1[6], p1[7]};                                  \
    __builtin_nontemporal_store(_w0, (f32x4*)(attnOut + _g0));                 \
    __builtin_nontemporal_store(_w1, (f32x4*)(attnOut + _g0 + 4));             \
    __builtin_nontemporal_store(_w2, (f32x4*)(attnOut + _g1));                 \
    __builtin_nontemporal_store(_w3, (f32x4*)(attnOut + _g1 + 4));             \
    *(ushort4*)(sP[buf] + e0) =                                                \
        make_ushort4(f2bf(p0[0]), f2bf(p0[1]), f2bf(p0[2]), f2bf(p0[3]));      \
    *(ushort4*)(sP[buf] + e0 + 4) =                                            \
        make_ushort4(f2bf(p0[4]), f2bf(p0[5]), f2bf(p0[6]), f2bf(p0[7]));      \
    *(ushort4*)(sP[buf] + e1) =                                                \
        make_ushort4(f2bf(p1[0]), f2bf(p1[1]), f2bf(p1[2]), f2bf(p1[3]));      \
    *(ushort4*)(sP[buf] + e1 + 4) =                                            \
        make_ushort4(f2bf(p1[4]), f2bf(p1[5]), f2bf(p1[6]), f2bf(p1[7]));      \
  } while (0)

  auto STAGEV = [&](int k0, int buf) {
#pragma unroll
    for (int r = 0; r < 4; ++r) {
      int e = (r * 256 + tid) * 8;
      int row = e >> 6, col = e & 63;
      g2l16(Vt + (long)(h * DK + row) * SEQ + k0 + col,
            (char*)sV[buf] + (size_t)e * 2);
    }
  };

  auto DO_MFMA = [&](int buf) {
#pragma unroll
    for (int ks = 0; ks < 64; ks += 32) {
      bf16x8 a[2], b[4];
#pragma unroll
      for (int i = 0; i < 2; i++)
        a[i] = *(const bf16x8*)&sP[buf][(wr * 32 + i * 16 + l16) * 64 + ks + quad * 8];
#pragma unroll
      for (int i = 0; i < 4; i++)
        b[i] = *(const bf16x8*)&sV[buf][(wc * 64 + i * 16 + l16) * 64 + ks + quad * 8];
#pragma unroll
      for (int mi = 0; mi < 2; mi++)
#pragma unroll
        for (int ni = 0; ni < 4; ni++)
          acc[mi][ni] = __builtin_amdgcn_mfma_f32_16x16x32_bf16(a[mi], b[ni], acc[mi][ni], 0, 0, 0);
    }
  };

  // Prologue: panel 0 -> regset A -> sP[0]; V panel 0 -> sV[0]; panel 1 -> regset B.
  LOADP(A, 0);
  STAGEV(0, 0);
  LOADP(B, 64);
  PROC(A, 0, 0);
  __syncthreads();

  // Steady state: two panels per trip; one barrier per panel.
  // Invariant at loop top: sP/sV[0] = panel i (ready), regset B = panel i+1 raw.
  for (int it = 0; it < 62; it += 2) {
    LOADP(A, (it + 2) * 64);        // prefetch panel i+2 (2 phases of slack)
    STAGEV((it + 1) * 64, 1);       // V panel i+1 -> sV[1]
    DO_MFMA(0);                     // compute panel i
    PROC(B, (it + 1) * 64, 1);      // normalize+attn-write panel i+1 -> sP[1]
    __syncthreads();
    LOADP(B, (it + 3) * 64);        // prefetch panel i+3
    STAGEV((it + 2) * 64, 0);       // V panel i+2 -> sV[0]
    DO_MFMA(1);                     // compute panel i+1
    PROC(A, (it + 2) * 64, 0);      // normalize+attn-write panel i+2 -> sP[0]
    __syncthreads();
  }
  // Epilogue: sP/sV[0] = panel 62, regset B = panel 63.
  STAGEV(63 * 64, 1);
  DO_MFMA(0);
  PROC(B, 63 * 64, 1);
  __syncthreads();
  DO_MFMA(1);

#undef LOADP
#undef PROC

#pragma unroll
  for (int mi = 0; mi < 2; mi++)
#pragma unroll
    for (int ni = 0; ni < 4; ni++)
#pragma unroll
      for (int r = 0; r < 4; r++) {
        long row = bm + wr * 32 + mi * 16 + quad * 4 + r;
        int col = h * DK + wc * 64 + ni * 16 + l16;
        Yb[row * (long)FDIM + col] = f2bf(acc[mi][ni][r]);
      }
}

// ---------------------------------------------------------------- launcher

extern "C" void kernel_launch(void* const* d_in, const int* in_sizes, int n_in,
                              void* d_out, int out_size, void* d_ws, size_t ws_size,
                              hipStream_t stream) {
  const float* x = (const float*)d_in[0];
  const float* Wq = (const float*)d_in[1];
  const float* Wk = (const float*)d_in[2];
  const float* Wv = (const float*)d_in[3];
  const float* Wo = (const float*)d_in[4];

  float* outY = (float*)d_out;              // 4096*1024
  float* attn = outY + (size_t)SEQ * FDIM;  // 8*4096*4096

  const size_t NX = (size_t)SEQ * FDIM;   // 4194304
  const size_t NW = (size_t)FDIM * FDIM;  // 1048576

  u16* p = (u16*)d_ws;
  u16* xhi = p; p += NX;
  u16* xlo = p; p += NX;
  u16* wqt_h = p; p += NW;
  u16* wqt_l = p; p += NW;
  u16* wkt_h = p; p += NW;   // wqt_h + 2*NW (z-stride for fused QK proj)
  u16* wkt_l = p; p += NW;
  u16* wvt = p; p += NW;
  u16* wot = p; p += NW;
  u16* Qhi = p; p += NX;
  u16* Qlo = p; p += NX;
  u16* Khi = p; p += NX;     // Qhi + 2*NX
  u16* Klo = p; p += NX;
  u16* Vb = p; p += NX;
  u16* Vt = p; p += NX;
  u16* Yb = p; p += NX;
  float* rowSum = (float*)p;
  float* invRow = rowSum + (size_t)NHEAD * SEQ;
  u16* expS = (u16*)(invRow + (size_t)NHEAD * SEQ);
  size_t need = (size_t)((char*)(expS + (size_t)NHEAD * SEQ * SEQ) - (char*)d_ws);
  bool bf16s = ws_size >= need;

  hipMemsetAsync(rowSum, 0, (size_t)NHEAD * SEQ * sizeof(float), stream);

  split_f32_bf16<<<dim3((NX / 4 + 255) / 256), 256, 0, stream>>>(
      (const float4*)x, xhi, xlo, NX / 4);

  dim3 tb(32, 8);
  transpose_split_w<<<dim3(32, 32), tb, 0, stream>>>(Wq, wqt_h, wqt_l, FDIM, 1);
  transpose_split_w<<<dim3(32, 32), tb, 0, stream>>>(Wk, wkt_h, wkt_l, FDIM, 1);
  transpose_split_w<<<dim3(32, 32), tb, 0, stream>>>(Wv, wvt, nullptr, FDIM, 0);
  transpose_split_w<<<dim3(32, 32), tb, 0, stream>>>(Wo, wot, nullptr, FDIM, 0);

  // Q and K projections fused (z=0 -> Q, z=1 -> K), split in/out
  gemm_bt<32, true, 2><<<dim3(8, 32, 2), 256, 0, stream>>>(
      xhi, xlo, wqt_h, wqt_l, Qhi, Qlo,
      1024, 1024, 1024, 1024, 0, (long)2 * NW, (long)2 * NX);

  // V projection (plain bf16) + transpose
  gemm_bt<64, false, 1><<<dim3(8, 32, 1), 256, 0, stream>>>(
      xhi, nullptr, wvt, nullptr, Vb, nullptr,
      1024, 1024, 1024, 1024, 0, 0, 0);
  transpose_bf16<<<dim3(32, 128), tb, 0, stream>>>(Vb, Vt, SEQ, FDIM);

  const float scale = 0.08838834764831845f;  // 1/sqrt(128)
  if (bf16s) {
    qk_exp<true><<<dim3(32, 32, NHEAD), 256, 0, stream>>>(
        Qhi, Qlo, Khi, Klo, expS, rowSum, scale);
  } else {
    qk_exp<false><<<dim3(32, 32, NHEAD), 256, 0, stream>>>(
        Qhi, Qlo, Khi, Klo, attn, rowSum, scale);
  }

  reciprocal_k<<<(NHEAD * SEQ + 255) / 256, 256, 0, stream>>>(rowSum, invRow, NHEAD * SEQ);

  if (bf16s) {
    pv_norm<true><<<dim3(1, 64, NHEAD), 256, 0, stream>>>(expS, invRow, attn, Vt, Yb);
  } else {
    pv_norm<false><<<dim3(1, 64, NHEAD), 256, 0, stream>>>(attn, invRow, attn, Vt, Yb);
  }

  // out = y @ Wo
  gemm_bt<64, false, 0><<<dim3(8, 32, 1), 256, 0, stream>>>(
      Yb, nullptr, wot, nullptr, outY, nullptr,
      1024, 1024, 1024, 1024, 0, 0, 0);
}